// Round 1
// baseline (105.416 us; speedup 1.0000x reference)
//
#include <hip/hip_runtime.h>

#define B_   256
#define N_   256
#define E_   32640
#define MH   128
#define MO   64
#define NH   64

typedef __bf16 bf16x8 __attribute__((ext_vector_type(8)));
typedef float  f32x4  __attribute__((ext_vector_type(4)));

__device__ __forceinline__ unsigned short cvt_bf16(float f) {
  unsigned u = __float_as_uint(f);
  u = (u + 0x7FFFu + ((u >> 16) & 1u)) >> 16;
  return (unsigned short)u;
}

// Swizzled LDS helpers: row-major [rows][rowbytes/2] bf16, byte ^= (row&7)<<4
__device__ __forceinline__ bf16x8 ldfrag(const unsigned short* base, int row, int kbyte, int rowbytes) {
  int byte = (row * rowbytes + kbyte) ^ ((row & 7) << 4);
  return *reinterpret_cast<const bf16x8*>(reinterpret_cast<const char*>(base) + byte);
}

__device__ __forceinline__ void st2(unsigned short* base, int row, int colbyte, int rowbytes, unsigned short v) {
  int byte = (row * rowbytes + colbyte) ^ ((row & 7) << 4);
  *reinterpret_cast<unsigned short*>(reinterpret_cast<char*>(base) + byte) = v;
}

__device__ __forceinline__ void stage_w(unsigned short* dst, const float* __restrict__ src,
                                        int elems, int lcols, int tid) {
  for (int t = tid; t < (elems >> 2); t += 512) {
    int idx = t << 2;
    const float4 v = *reinterpret_cast<const float4*>(src + idx);
    int row = idx >> lcols;
    ushort4 u = make_ushort4(cvt_bf16(v.x), cvt_bf16(v.y), cvt_bf16(v.z), cvt_bf16(v.w));
    int byte = (idx * 2) ^ ((row & 7) << 4);
    *reinterpret_cast<ushort4*>(reinterpret_cast<char*>(dst) + byte) = u;
  }
}

__global__ __launch_bounds__(512, 2) void mlpdec_kernel(
    const float* __restrict__ se_g,
    const float* __restrict__ w1,  const float* __restrict__ b1,
    const float* __restrict__ w2,  const float* __restrict__ b2,
    const float* __restrict__ wo1, const float* __restrict__ bo1,
    const float* __restrict__ wo2, const float* __restrict__ bo2,
    const float* __restrict__ wo3, const float* __restrict__ bo3,
    float* __restrict__ out)
{
  // LDS: weights (bf16, swizzled) + 3 A-chunks + H/X/P scratch + biases + reduce
  __shared__ __align__(16) unsigned short sW1[MH * N_];   // [128][256]  65536 B
  __shared__ __align__(16) unsigned short sW2[MO * MH];   // [64][128]   16384 B
  __shared__ __align__(16) unsigned short sWO1[NH * MO];  // [64][64]     8192 B
  __shared__ __align__(16) unsigned short sWO2[NH * NH];  // [64][64]     8192 B
  __shared__ __align__(16) unsigned short sA[3][32 * N_]; // 3x[32][256] 49152 B
  __shared__ __align__(16) unsigned short sHXP[32 * MH];  // H[32][128]; X@+0, P@+4096B
  __shared__ float sB1[MH], sB2[MO], sBO1[NH], sBO2[NH], sWo3[2 * NH], sBo3[2];
  __shared__ float sAccW[8][64];
  __shared__ float sMean[64];

  const int tid = threadIdx.x;
  const int b   = blockIdx.x;
  const int w   = tid >> 6;     // wave 0..7
  const int l   = tid & 63;
  const int l15 = l & 15;
  const int lk  = l >> 4;       // k-group 0..3
  const int kb0 = lk * 16;      // byte offset of this lane's 8 bf16 within a K=32 step

  // ---- stage weights (bf16, swizzled) + biases ----
  stage_w(sW1,  w1,  MH * N_, 8, tid);
  stage_w(sW2,  w2,  MO * MH, 7, tid);
  stage_w(sWO1, wo1, NH * MO, 6, tid);
  stage_w(sWO2, wo2, NH * NH, 6, tid);
  if (tid < 128) sB1[tid]  = b1[tid];
  if (tid < 64)  { sB2[tid] = b2[tid]; sBO1[tid] = bo1[tid]; sBO2[tid] = bo2[tid]; }
  if (tid < 128) sWo3[tid] = wo3[tid];
  if (tid < 2)   sBo3[tid] = bo3[tid];
  reinterpret_cast<float*>(sAccW)[tid] = 0.f;
  __syncthreads();

  const float4* seB = reinterpret_cast<const float4*>(se_g) + (size_t)b * E_;
  unsigned short* sH = sHXP;
  unsigned short* sX = sHXP;            // reuse (head phase, H dead)
  unsigned short* sP = sHXP + 32 * 64;  // +4096 B

  const int tr  = w >> 2;        // output tile-row (0..1) of the 32-row chunk
  const int tc2 = w & 3;         // 16-col tile for the 64-wide GEMMs
  const int tcB = (w & 3) * 2;   // 2 x 16-col tiles for the 128-wide GEMM1

  for (int r0 = 0; r0 < N_; r0 += 32) {
    // ---- stage 3 A-chunks [32][256] from sparse_edges ----
    // (a) upper triangle: row-contiguous edge indices, coalesced float4 reads
    #pragma unroll
    for (int rr = 0; rr < 4; ++rr) {
      int lr = (w << 2) + rr;          // local row 0..31
      int gi = r0 + lr;                // global row
      int cnt = 255 - gi;
      int ubase = gi * 255 - ((gi * (gi - 1)) >> 1);
      for (int jj = l; jj < cnt; jj += 64) {
        float4 v = seB[ubase + jj];
        int cb = (gi + 1 + jj) * 2;
        st2(sA[0], lr, cb, 512, cvt_bf16(v.y));
        st2(sA[1], lr, cb, 512, cvt_bf16(v.z));
        st2(sA[2], lr, cb, 512, cvt_bf16(v.w));
      }
    }
    // (b) lower triangle via column strips: for fixed j, u(j,i) contiguous in i
    {
      int sub = tid >> 5, l32 = tid & 31;
      for (int j = sub; j < r0 + 31; j += 16) {
        int i0  = (j + 1 > r0) ? (j + 1) : r0;
        int cnt = r0 + 32 - i0;
        if (l32 < cnt) {
          int i = i0 + l32;
          int u = j * 255 - ((j * (j - 1)) >> 1) + (i - j - 1);
          float4 v = seB[u];
          int lr = i - r0, cb = j * 2;
          st2(sA[0], lr, cb, 512, cvt_bf16(v.y));
          st2(sA[1], lr, cb, 512, cvt_bf16(v.z));
          st2(sA[2], lr, cb, 512, cvt_bf16(v.w));
        }
      }
    }
    // diagonal = 0
    if (tid < 32) {
      int cb = (r0 + tid) * 2;
      st2(sA[0], tid, cb, 512, 0);
      st2(sA[1], tid, cb, 512, 0);
      st2(sA[2], tid, cb, 512, 0);
    }
    __syncthreads();

    f32x4 outAcc = {0.f, 0.f, 0.f, 0.f};

    for (int e = 0; e < 3; ++e) {
      // GEMM1: H[32][128] = relu(A @ W1^T + b1)
      {
        f32x4 acc0 = {0,0,0,0}, acc1 = {0,0,0,0};
        const unsigned short* sAe = sA[e];
        int arow  = tr * 16 + l15;
        int brow0 = (tcB + 0) * 16 + l15;
        int brow1 = (tcB + 1) * 16 + l15;
        #pragma unroll
        for (int ks = 0; ks < 8; ++ks) {
          int kb = ks * 64 + kb0;
          bf16x8 a   = ldfrag(sAe, arow,  kb, 512);
          bf16x8 bf0 = ldfrag(sW1, brow0, kb, 512);
          bf16x8 bf1 = ldfrag(sW1, brow1, kb, 512);
          acc0 = __builtin_amdgcn_mfma_f32_16x16x32_bf16(a, bf0, acc0, 0, 0, 0);
          acc1 = __builtin_amdgcn_mfma_f32_16x16x32_bf16(a, bf1, acc1, 0, 0, 0);
        }
        int   c0 = (tcB + 0) * 16 + l15, c1 = (tcB + 1) * 16 + l15;
        float bias0 = sB1[c0], bias1 = sB1[c1];
        #pragma unroll
        for (int r = 0; r < 4; ++r) {
          int hrow = tr * 16 + lk * 4 + r;
          st2(sH, hrow, c0 * 2, 256, cvt_bf16(fmaxf(acc0[r] + bias0, 0.f)));
          st2(sH, hrow, c1 * 2, 256, cvt_bf16(fmaxf(acc1[r] + bias1, 0.f)));
        }
      }
      __syncthreads();
      // GEMM2: M[32][64] = relu(H @ W2^T + b2); weighted accumulate
      {
        f32x4 acc = {0,0,0,0};
        int arow = tr * 16 + l15;
        int brow = tc2 * 16 + l15;
        #pragma unroll
        for (int ks = 0; ks < 4; ++ks) {
          int kb = ks * 64 + kb0;
          bf16x8 a  = ldfrag(sH,  arow, kb, 256);
          bf16x8 bb = ldfrag(sW2, brow, kb, 256);
          acc = __builtin_amdgcn_mfma_f32_16x16x32_bf16(a, bb, acc, 0, 0, 0);
        }
        float bias = sB2[tc2 * 16 + l15];
        float wte  = 0.2f * (float)(e + 1);
        #pragma unroll
        for (int r = 0; r < 4; ++r)
          outAcc[r] += wte * fmaxf(acc[r] + bias, 0.f);
      }
      __syncthreads();  // before next e overwrites sH
    }

    // ---- head: P1 = relu(X@WO1^T+bo1); P2 = relu(P1@WO2^T+bo2); row-sum ----
    {
      int col = tc2 * 16 + l15;
      #pragma unroll
      for (int r = 0; r < 4; ++r) {
        int xr = tr * 16 + lk * 4 + r;
        st2(sX, xr, col * 2, 128, cvt_bf16(outAcc[r]));
      }
    }
    __syncthreads();
    {
      f32x4 acc = {0,0,0,0};
      int arow = tr * 16 + l15;
      int brow = tc2 * 16 + l15;
      #pragma unroll
      for (int ks = 0; ks < 2; ++ks) {
        int kb = ks * 64 + kb0;
        bf16x8 a  = ldfrag(sX,   arow, kb, 128);
        bf16x8 bb = ldfrag(sWO1, brow, kb, 128);
        acc = __builtin_amdgcn_mfma_f32_16x16x32_bf16(a, bb, acc, 0, 0, 0);
      }
      float bias = sBO1[tc2 * 16 + l15];
      #pragma unroll
      for (int r = 0; r < 4; ++r) {
        int pr = tr * 16 + lk * 4 + r;
        st2(sP, pr, (tc2 * 16 + l15) * 2, 128, cvt_bf16(fmaxf(acc[r] + bias, 0.f)));
      }
    }
    __syncthreads();
    {
      f32x4 acc = {0,0,0,0};
      int arow = tr * 16 + l15;
      int brow = tc2 * 16 + l15;
      #pragma unroll
      for (int ks = 0; ks < 2; ++ks) {
        int kb = ks * 64 + kb0;
        bf16x8 a  = ldfrag(sP,   arow, kb, 128);
        bf16x8 bb = ldfrag(sWO2, brow, kb, 128);
        acc = __builtin_amdgcn_mfma_f32_16x16x32_bf16(a, bb, acc, 0, 0, 0);
      }
      float bias = sBO2[tc2 * 16 + l15];
      float s = 0.f;
      #pragma unroll
      for (int r = 0; r < 4; ++r) s += fmaxf(acc[r] + bias, 0.f);
      s += __shfl_xor(s, 16);
      s += __shfl_xor(s, 32);
      if (lk == 0) sAccW[w][tc2 * 16 + l15] += s;  // wave-private row, lane-unique col
    }
    __syncthreads();  // protect sP/sX before next chunk's GEMM1 H-writes
  }

  // ---- mean over atoms + final 64->2 projection ----
  if (tid < 64) {
    float s = 0.f;
    #pragma unroll
    for (int ww = 0; ww < 8; ++ww) s += sAccW[ww][tid];
    sMean[tid] = s * (1.0f / 256.0f);
  }
  __syncthreads();
  if (tid < 128) {
    int c = tid >> 6;
    float v = sMean[l] * sWo3[c * 64 + l];
    #pragma unroll
    for (int off = 32; off > 0; off >>= 1) v += __shfl_down(v, off);
    if (l == 0) out[b * 2 + c] = v + sBo3[c];
  }
}

extern "C" void kernel_launch(void* const* d_in, const int* in_sizes, int n_in,
                              void* d_out, int out_size, void* d_ws, size_t ws_size,
                              hipStream_t stream) {
  (void)in_sizes; (void)n_in; (void)d_ws; (void)ws_size; (void)out_size;
  const float* se  = (const float*)d_in[1];   // d_in[0] = `inputs` — shape-only, never read
  const float* w1  = (const float*)d_in[2];
  const float* b1  = (const float*)d_in[3];
  const float* w2  = (const float*)d_in[4];
  const float* b2  = (const float*)d_in[5];
  const float* wo1 = (const float*)d_in[6];
  const float* bo1 = (const float*)d_in[7];
  const float* wo2 = (const float*)d_in[8];
  const float* bo2 = (const float*)d_in[9];
  const float* wo3 = (const float*)d_in[10];
  const float* bo3 = (const float*)d_in[11];
  mlpdec_kernel<<<dim3(256), dim3(512), 0, stream>>>(
      se, w1, b1, w2, b2, wo1, bo1, wo2, bo2, wo3, bo3, (float*)d_out);
}

// Round 2
// 101.159 us; speedup vs baseline: 1.0421x; 1.0421x over previous
//
#include <hip/hip_runtime.h>

#define N_   256
#define E_   32640

typedef __bf16 bf16x8 __attribute__((ext_vector_type(8)));
typedef unsigned short u16x8 __attribute__((ext_vector_type(8)));
typedef float f32x4 __attribute__((ext_vector_type(4)));

__device__ __forceinline__ unsigned short cvt_bf16(float f) {
  unsigned u = __float_as_uint(f);
  u = (u + 0x7FFFu + ((u >> 16) & 1u)) >> 16;
  return (unsigned short)u;
}

// Swizzled LDS helpers: row-major bf16, byte ^= (row&7)<<4
__device__ __forceinline__ bf16x8 ldfrag(const unsigned short* base, int row, int kbyte, int rowbytes) {
  int byte = (row * rowbytes + kbyte) ^ ((row & 7) << 4);
  return *reinterpret_cast<const bf16x8*>(reinterpret_cast<const char*>(base) + byte);
}

__device__ __forceinline__ void st2(unsigned short* base, int row, int colbyte, int rowbytes, unsigned short v) {
  int byte = (row * rowbytes + colbyte) ^ ((row & 7) << 4);
  *reinterpret_cast<unsigned short*>(reinterpret_cast<char*>(base) + byte) = v;
}

__device__ __forceinline__ bf16x8 pack8(float4 lo, float4 hi) {
  u16x8 u;
  u[0] = cvt_bf16(lo.x); u[1] = cvt_bf16(lo.y); u[2] = cvt_bf16(lo.z); u[3] = cvt_bf16(lo.w);
  u[4] = cvt_bf16(hi.x); u[5] = cvt_bf16(hi.y); u[6] = cvt_bf16(hi.z); u[7] = cvt_bf16(hi.w);
  return __builtin_bit_cast(bf16x8, u);
}

__global__ __launch_bounds__(1024, 4) void mlpdec_kernel(
    const float* __restrict__ se_g,
    const float* __restrict__ w1,  const float* __restrict__ b1,
    const float* __restrict__ w2,  const float* __restrict__ b2,
    const float* __restrict__ wo1, const float* __restrict__ bo1,
    const float* __restrict__ wo2, const float* __restrict__ bo2,
    const float* __restrict__ wo3, const float* __restrict__ bo3,
    float* __restrict__ out)
{
  __shared__ __align__(16) unsigned short sA[3][64 * N_];  // 3x[64][256] bf16  96 KB
  __shared__ __align__(16) unsigned short sH[64 * 128];    // 16 KB; overlay X@0, P@+8192B
  __shared__ __align__(16) unsigned short sWO1[64 * 64];   // 8 KB
  __shared__ __align__(16) unsigned short sWO2[64 * 64];   // 8 KB
  __shared__ float sB1[128], sB2[64], sBO1[64], sBO2[64], sWo3[128], sBo3[2];
  __shared__ float sAccW[16][64];
  __shared__ float sMean[64];

  const int tid = threadIdx.x;
  const int b   = blockIdx.x;
  const int w   = tid >> 6;     // wave 0..15
  const int l   = tid & 63;
  const int l15 = l & 15;
  const int lk  = l >> 4;       // 0..3
  const int kb0 = lk * 16;      // byte offset within K=32 step

  // wave -> tile assignments
  const int c1 = w & 7;         // GEMM1 col-tile (of 8); rowtiles rb, rb+2
  const int rb = w >> 3;
  const int c2 = w & 3;         // GEMM2/head col-tile (of 4)
  const int r2 = w >> 2;        // GEMM2/head row-tile (of 4)

  // ---- W1/W2 B-fragments -> registers (fixed per wave for whole kernel) ----
  bf16x8 W1f[8];
  {
    const float* p = w1 + (c1 * 16 + l15) * 256 + lk * 8;
    #pragma unroll
    for (int ks = 0; ks < 8; ++ks) {
      float4 lo = *reinterpret_cast<const float4*>(p + ks * 32);
      float4 hi = *reinterpret_cast<const float4*>(p + ks * 32 + 4);
      W1f[ks] = pack8(lo, hi);
    }
  }
  bf16x8 W2f[4];
  {
    const float* p = w2 + (c2 * 16 + l15) * 128 + lk * 8;
    #pragma unroll
    for (int ks = 0; ks < 4; ++ks) {
      float4 lo = *reinterpret_cast<const float4*>(p + ks * 32);
      float4 hi = *reinterpret_cast<const float4*>(p + ks * 32 + 4);
      W2f[ks] = pack8(lo, hi);
    }
  }

  // ---- stage WO1/WO2 (bf16 swizzled, rowbytes 128) + biases ----
  {
    int t = tid;  // 4096 elems / 4 = 1024 slots: one per thread
    int idx = t << 2;
    {
      const float4 v = *reinterpret_cast<const float4*>(wo1 + idx);
      int row = idx >> 6;
      ushort4 u = make_ushort4(cvt_bf16(v.x), cvt_bf16(v.y), cvt_bf16(v.z), cvt_bf16(v.w));
      int byte = (idx * 2) ^ ((row & 7) << 4);
      *reinterpret_cast<ushort4*>(reinterpret_cast<char*>(sWO1) + byte) = u;
    }
    {
      const float4 v = *reinterpret_cast<const float4*>(wo2 + idx);
      int row = idx >> 6;
      ushort4 u = make_ushort4(cvt_bf16(v.x), cvt_bf16(v.y), cvt_bf16(v.z), cvt_bf16(v.w));
      int byte = (idx * 2) ^ ((row & 7) << 4);
      *reinterpret_cast<ushort4*>(reinterpret_cast<char*>(sWO2) + byte) = u;
    }
  }
  if (tid < 128) sB1[tid] = b1[tid];
  if (tid < 64)  { sB2[tid] = b2[tid]; sBO1[tid] = bo1[tid]; sBO2[tid] = bo2[tid]; }
  if (tid < 128) sWo3[tid] = wo3[tid];
  if (tid < 2)   sBo3[tid] = bo3[tid];
  reinterpret_cast<float*>(sAccW)[tid] = 0.f;   // 16*64 = 1024 floats, one per thread
  __syncthreads();

  const float4* seB = reinterpret_cast<const float4*>(se_g) + (size_t)b * E_;
  unsigned short* sX = sH;              // head reuse
  unsigned short* sP = sH + 64 * 64;    // +8192 B

  for (int r0 = 0; r0 < N_; r0 += 64) {
    // ---- stage 3 A-chunks [64][256] bf16 from sparse_edges ----
    // (a) upper triangle: row-contiguous float4 reads
    #pragma unroll
    for (int rr = 0; rr < 4; ++rr) {
      int lr = (w << 2) + rr;          // local row 0..63
      int gi = r0 + lr;
      int cnt = 255 - gi;
      int ubase = gi * 255 - ((gi * (gi - 1)) >> 1);
      for (int jj = l; jj < cnt; jj += 64) {
        float4 v = seB[ubase + jj];
        int cb = (gi + 1 + jj) * 2;
        st2(sA[0], lr, cb, 512, cvt_bf16(v.y));
        st2(sA[1], lr, cb, 512, cvt_bf16(v.z));
        st2(sA[2], lr, cb, 512, cvt_bf16(v.w));
      }
    }
    // (b) lower triangle via column strips: for fixed j, u(j,i) contiguous in i
    for (int j = w; j < r0 + 63; j += 16) {
      int i0  = (j + 1 > r0) ? (j + 1) : r0;
      int cnt = r0 + 64 - i0;
      if (l < cnt) {
        int i = i0 + l;
        int u = j * 255 - ((j * (j - 1)) >> 1) + (i - j - 1);
        float4 v = seB[u];
        int lr = i - r0, cb = j * 2;
        st2(sA[0], lr, cb, 512, cvt_bf16(v.y));
        st2(sA[1], lr, cb, 512, cvt_bf16(v.z));
        st2(sA[2], lr, cb, 512, cvt_bf16(v.w));
      }
    }
    // diagonal = 0
    if (tid < 64) {
      int cb = (r0 + tid) * 2;
      st2(sA[0], tid, cb, 512, 0);
      st2(sA[1], tid, cb, 512, 0);
      st2(sA[2], tid, cb, 512, 0);
    }
    __syncthreads();

    f32x4 outAcc = {0.f, 0.f, 0.f, 0.f};

    for (int e = 0; e < 3; ++e) {
      // GEMM1: H[64][128] = relu(A @ W1^T + b1); wave does rowtiles rb, rb+2 of coltile c1
      {
        f32x4 acc0 = {0,0,0,0}, acc1 = {0,0,0,0};
        const unsigned short* sAe = sA[e];
        int arow0 = rb * 16 + l15;
        int arow1 = (rb + 2) * 16 + l15;
        #pragma unroll
        for (int ks = 0; ks < 8; ++ks) {
          int kb = ks * 64 + kb0;
          bf16x8 a0 = ldfrag(sAe, arow0, kb, 512);
          bf16x8 a1 = ldfrag(sAe, arow1, kb, 512);
          acc0 = __builtin_amdgcn_mfma_f32_16x16x32_bf16(a0, W1f[ks], acc0, 0, 0, 0);
          acc1 = __builtin_amdgcn_mfma_f32_16x16x32_bf16(a1, W1f[ks], acc1, 0, 0, 0);
        }
        int cc = c1 * 16 + l15;
        float bias = sB1[cc];
        #pragma unroll
        for (int r = 0; r < 4; ++r) {
          st2(sH, rb * 16 + lk * 4 + r,       cc * 2, 256, cvt_bf16(fmaxf(acc0[r] + bias, 0.f)));
          st2(sH, (rb + 2) * 16 + lk * 4 + r, cc * 2, 256, cvt_bf16(fmaxf(acc1[r] + bias, 0.f)));
        }
      }
      __syncthreads();
      // GEMM2: M[64][64] = relu(H @ W2^T + b2); weighted accumulate. 1 tile/wave (r2,c2)
      {
        f32x4 acc = {0,0,0,0};
        int arow = r2 * 16 + l15;
        #pragma unroll
        for (int ks = 0; ks < 4; ++ks) {
          bf16x8 a = ldfrag(sH, arow, ks * 64 + kb0, 256);
          acc = __builtin_amdgcn_mfma_f32_16x16x32_bf16(a, W2f[ks], acc, 0, 0, 0);
        }
        float bias = sB2[c2 * 16 + l15];
        float wte  = 0.2f * (float)(e + 1);
        #pragma unroll
        for (int r = 0; r < 4; ++r)
          outAcc[r] += wte * fmaxf(acc[r] + bias, 0.f);
      }
      __syncthreads();  // before next e overwrites sH
    }

    // ---- head on this 64-row chunk ----
    {
      int col = c2 * 16 + l15;
      #pragma unroll
      for (int r = 0; r < 4; ++r)
        st2(sX, r2 * 16 + lk * 4 + r, col * 2, 128, cvt_bf16(outAcc[r]));
    }
    __syncthreads();
    {
      f32x4 acc = {0,0,0,0};
      int arow = r2 * 16 + l15;
      int brow = c2 * 16 + l15;
      #pragma unroll
      for (int ks = 0; ks < 2; ++ks) {
        bf16x8 a  = ldfrag(sX,   arow, ks * 64 + kb0, 128);
        bf16x8 bb = ldfrag(sWO1, brow, ks * 64 + kb0, 128);
        acc = __builtin_amdgcn_mfma_f32_16x16x32_bf16(a, bb, acc, 0, 0, 0);
      }
      float bias = sBO1[c2 * 16 + l15];
      #pragma unroll
      for (int r = 0; r < 4; ++r)
        st2(sP, r2 * 16 + lk * 4 + r, (c2 * 16 + l15) * 2, 128, cvt_bf16(fmaxf(acc[r] + bias, 0.f)));
    }
    __syncthreads();
    {
      f32x4 acc = {0,0,0,0};
      int arow = r2 * 16 + l15;
      int brow = c2 * 16 + l15;
      #pragma unroll
      for (int ks = 0; ks < 2; ++ks) {
        bf16x8 a  = ldfrag(sP,   arow, ks * 64 + kb0, 128);
        bf16x8 bb = ldfrag(sWO2, brow, ks * 64 + kb0, 128);
        acc = __builtin_amdgcn_mfma_f32_16x16x32_bf16(a, bb, acc, 0, 0, 0);
      }
      float bias = sBO2[c2 * 16 + l15];
      float s = 0.f;
      #pragma unroll
      for (int r = 0; r < 4; ++r) s += fmaxf(acc[r] + bias, 0.f);
      s += __shfl_xor(s, 16);
      s += __shfl_xor(s, 32);
      if (lk == 0) sAccW[w][c2 * 16 + l15] += s;  // wave-private row
    }
    __syncthreads();  // protect sH/sX/sP + sA before next chunk
  }

  // ---- mean over atoms + final 64->2 projection ----
  if (tid < 64) {
    float s = 0.f;
    #pragma unroll
    for (int ww = 0; ww < 16; ++ww) s += sAccW[ww][tid];
    sMean[tid] = s * (1.0f / 256.0f);
  }
  __syncthreads();
  if (tid < 128) {
    int c = tid >> 6;
    float v = sMean[l] * sWo3[c * 64 + l];
    #pragma unroll
    for (int off = 32; off > 0; off >>= 1) v += __shfl_down(v, off);
    if (l == 0) out[b * 2 + c] = v + sBo3[c];
  }
}

extern "C" void kernel_launch(void* const* d_in, const int* in_sizes, int n_in,
                              void* d_out, int out_size, void* d_ws, size_t ws_size,
                              hipStream_t stream) {
  (void)in_sizes; (void)n_in; (void)d_ws; (void)ws_size; (void)out_size;
  const float* se  = (const float*)d_in[1];   // d_in[0] = `inputs` — shape-only, never read
  const float* w1  = (const float*)d_in[2];
  const float* b1  = (const float*)d_in[3];
  const float* w2  = (const float*)d_in[4];
  const float* b2  = (const float*)d_in[5];
  const float* wo1 = (const float*)d_in[6];
  const float* bo1 = (const float*)d_in[7];
  const float* wo2 = (const float*)d_in[8];
  const float* bo2 = (const float*)d_in[9];
  const float* wo3 = (const float*)d_in[10];
  const float* bo3 = (const float*)d_in[11];
  mlpdec_kernel<<<dim3(256), dim3(1024), 0, stream>>>(
      se, w1, b1, w2, b2, wo1, bo1, wo2, bo2, wo3, bo3, (float*)d_out);
}